// Round 2
// baseline (600.476 us; speedup 1.0000x reference)
//
#include <hip/hip_runtime.h>
#include <hip/hip_bf16.h>
#include <cstdint>
#include <cstddef>

#define D_MODEL 1024
#define N_HEAD  16
#define DH      64
#define SEQ     2048
#define BATCH   4

typedef __attribute__((ext_vector_type(8))) __bf16 bf16x8;
typedef __attribute__((ext_vector_type(8))) unsigned short u16x8;
typedef __attribute__((ext_vector_type(4))) float f32x4;

static __device__ __forceinline__ unsigned short f2bf(float f) {
  unsigned int u = __builtin_bit_cast(unsigned int, f);
  u += 0x7fffu + ((u >> 16) & 1u);   // round-to-nearest-even
  return (unsigned short)(u >> 16);
}

static __device__ __forceinline__ void gll16(const unsigned short* g, unsigned short* l) {
  __builtin_amdgcn_global_load_lds((const __attribute__((address_space(1))) void*)g,
                                   (__attribute__((address_space(3))) void*)l, 16, 0, 0);
}

// bijective XCD swizzle (nwg % 8 == 0): contiguous chunk of nwg/8 per XCD
static __device__ __forceinline__ int xcd_swz(int bid, int nwg) {
  const int cpx = nwg >> 3;
  return (bid & 7) * cpx + (bid >> 3);
}

// ---------------- fp32 -> bf16 convert (8 elems/lane) ----------------
__global__ void cvtk(const float* __restrict__ in, unsigned short* __restrict__ out, int n) {
  int stride = gridDim.x * blockDim.x;
  for (int i = blockIdx.x * blockDim.x + threadIdx.x; i * 8 < n; i += stride) {
    float4 a = *(const float4*)(in + (size_t)i * 8);
    float4 b = *(const float4*)(in + (size_t)i * 8 + 4);
    u16x8 o;
    o[0] = f2bf(a.x); o[1] = f2bf(a.y); o[2] = f2bf(a.z); o[3] = f2bf(a.w);
    o[4] = f2bf(b.x); o[5] = f2bf(b.y); o[6] = f2bf(b.z); o[7] = f2bf(b.w);
    *(u16x8*)(out + (size_t)i * 8) = o;
  }
}

// ---------------- NT GEMM: C[m,n] = sum_k A[m,k]*B[n,k] + bias[n] ----------------
// A: [M,K] bf16 row-major, B: [N,K] bf16 row-major (x @ W^T, W=[N,K]).
// m97 structure: 128x128 tile, BK=32, 4 waves each 64x64 (4x4 frags of 16x16x32).
// 1D grid, XCD-swizzled.
template<int OUTF32>
__global__ __launch_bounds__(256) void gemm_bt(
    const unsigned short* __restrict__ A,
    const unsigned short* __restrict__ B,
    const float* __restrict__ bias,
    unsigned short* __restrict__ Cb, float* __restrict__ Cf,
    int M, int N, int K)
{
  __shared__ unsigned short As[128 * 32];
  __shared__ unsigned short Bs[128 * 32];
  const int t  = threadIdx.x;
  const int w  = t >> 6, l = t & 63;
  const int lr = l & 15, lk = l >> 4;

  const int nbx = N >> 7;
  const int swz = xcd_swz(blockIdx.x, gridDim.x);
  const int bn0 = (swz % nbx) * 128, bm0 = (swz / nbx) * 128;
  const int wm = (w >> 1) * 64, wn = (w & 1) * 64;

  f32x4 acc[4][4] = {};
  const int NT = K >> 5;

  auto stage = [&](int kt) {
    const int k0 = kt << 5;
#pragma unroll
    for (int i = 0; i < 2; ++i) {
      int c = i * 256 + t;               // 512 chunks of 16B per 128x32 tile
      int row = c >> 2, ko = (c & 3) << 3;
      int ub = __builtin_amdgcn_readfirstlane((c & ~63) * 8);  // wave-uniform LDS base
      gll16(A + (size_t)(bm0 + row) * K + k0 + ko, As + ub);
      gll16(B + (size_t)(bn0 + row) * K + k0 + ko, Bs + ub);
    }
  };

  stage(0);
  for (int kt = 0; kt < NT; ++kt) {
    asm volatile("s_waitcnt vmcnt(0)" ::: "memory");
    __syncthreads();
    bf16x8 af[4], bfr[4];
#pragma unroll
    for (int i = 0; i < 4; ++i) {
      af[i]  = __builtin_bit_cast(bf16x8, *(const u16x8*)(As + (wm + i * 16 + lr) * 32 + lk * 8));
      bfr[i] = __builtin_bit_cast(bf16x8, *(const u16x8*)(Bs + (wn + i * 16 + lr) * 32 + lk * 8));
    }
#pragma unroll
    for (int mi = 0; mi < 4; ++mi)
#pragma unroll
      for (int ni = 0; ni < 4; ++ni)
        acc[mi][ni] = __builtin_amdgcn_mfma_f32_16x16x32_bf16(af[mi], bfr[ni], acc[mi][ni], 0, 0, 0);
    __syncthreads();
    if (kt + 1 < NT) stage(kt + 1);
  }

  float bv[4];
#pragma unroll
  for (int ni = 0; ni < 4; ++ni) bv[ni] = bias[bn0 + wn + ni * 16 + lr];
#pragma unroll
  for (int mi = 0; mi < 4; ++mi)
#pragma unroll
    for (int ni = 0; ni < 4; ++ni) {
      const int col = bn0 + wn + ni * 16 + lr;
#pragma unroll
      for (int r = 0; r < 4; ++r) {
        const int row = bm0 + wm + mi * 16 + lk * 4 + r;
        float v = acc[mi][ni][r] + bv[ni];
        if (OUTF32) Cf[(size_t)row * N + col] = v;
        else        Cb[(size_t)row * N + col] = f2bf(v);
      }
    }
}

// ---------------- flash attention fwd ----------------
// 1D grid (SEQ/128 * N_HEAD * BATCH = 1024), XCD-swizzled; 256 thr (4 waves x 32 Q-rows).
// KV tile = 64. K row-major in LDS, V transposed in LDS, P round-trips via LDS.
__global__ __launch_bounds__(256) void attn_fwd(
    const unsigned short* __restrict__ Qp,
    const unsigned short* __restrict__ Kp,
    const unsigned short* __restrict__ Vp,
    unsigned short* __restrict__ Ao)
{
  __shared__ unsigned short Ks[64][72];   // [j][d] pad->144B rows (16B aligned)
  __shared__ unsigned short Vt[64][72];   // [d][j]
  __shared__ unsigned short Ps[128][72];  // [qrow][j], per-wave disjoint 32-row bands

  const int t = threadIdx.x, w = t >> 6, l = t & 63;
  const int lr = l & 15, lk = l >> 4;
  const int swz = xcd_swz(blockIdx.x, gridDim.x);
  const int qt = swz & 15, h = (swz >> 4) & 15, b = swz >> 8;
  const int hoff = h * DH;
  const int q0 = qt * 128 + w * 32;

  // Q fragments, resident for whole kernel: rows q0..q0+31, d=0..63
  bf16x8 qf[2][2];
#pragma unroll
  for (int mi = 0; mi < 2; ++mi)
#pragma unroll
    for (int kk = 0; kk < 2; ++kk) {
      const int row = q0 + mi * 16 + lr;
      qf[mi][kk] = __builtin_bit_cast(bf16x8,
        *(const u16x8*)(Qp + (size_t)(b * SEQ + row) * D_MODEL + hoff + kk * 32 + lk * 8));
    }

  f32x4 acc[2][4] = {};
  float mrun[2][4], lrun[2][4];
#pragma unroll
  for (int mi = 0; mi < 2; ++mi)
#pragma unroll
    for (int r = 0; r < 4; ++r) { mrun[mi][r] = -1e30f; lrun[mi][r] = 0.f; }

  for (int jt = 0; jt < SEQ / 64; ++jt) {
    __syncthreads();   // protect Ks/Vt from previous iteration's readers
    // ---- stage K (row-major) and V (transposed) ----
#pragma unroll
    for (int i = 0; i < 2; ++i) {
      int c = i * 256 + t;                 // 512 chunks of 8 elems
      int row = c >> 3, ko = (c & 7) << 3;
      const size_t gbase = (size_t)(b * SEQ + jt * 64 + row) * D_MODEL + hoff + ko;
      u16x8 kv = *(const u16x8*)(Kp + gbase);
      *(u16x8*)&Ks[row][ko] = kv;
      u16x8 vv = *(const u16x8*)(Vp + gbase);
#pragma unroll
      for (int jj = 0; jj < 8; ++jj) Vt[ko + jj][row] = vv[jj];
    }
    __syncthreads();

    // ---- S = (Q K^T) * 1/8 ----
    bf16x8 kb[4][2];
#pragma unroll
    for (int ni = 0; ni < 4; ++ni)
#pragma unroll
      for (int kk = 0; kk < 2; ++kk)
        kb[ni][kk] = __builtin_bit_cast(bf16x8, *(const u16x8*)(&Ks[ni * 16 + lr][kk * 32 + lk * 8]));

    f32x4 s[2][4];
#pragma unroll
    for (int mi = 0; mi < 2; ++mi)
#pragma unroll
      for (int ni = 0; ni < 4; ++ni) {
        f32x4 z = {};
        z = __builtin_amdgcn_mfma_f32_16x16x32_bf16(qf[mi][0], kb[ni][0], z, 0, 0, 0);
        z = __builtin_amdgcn_mfma_f32_16x16x32_bf16(qf[mi][1], kb[ni][1], z, 0, 0, 0);
        s[mi][ni] = z;
      }

    // ---- online softmax (rows live in 16-lane groups: same lk) ----
#pragma unroll
    for (int mi = 0; mi < 2; ++mi) {
#pragma unroll
      for (int r = 0; r < 4; ++r) {
        float vmax = -1e30f;
#pragma unroll
        for (int ni = 0; ni < 4; ++ni) { s[mi][ni][r] *= 0.125f; vmax = fmaxf(vmax, s[mi][ni][r]); }
#pragma unroll
        for (int off = 1; off < 16; off <<= 1) vmax = fmaxf(vmax, __shfl_xor(vmax, off));
        const float mnew = fmaxf(mrun[mi][r], vmax);
        const float alpha = __expf(mrun[mi][r] - mnew);
        mrun[mi][r] = mnew;
        float sum = 0.f;
#pragma unroll
        for (int ni = 0; ni < 4; ++ni) {
          float p = __expf(s[mi][ni][r] - mnew);
          s[mi][ni][r] = p; sum += p;
        }
#pragma unroll
        for (int off = 1; off < 16; off <<= 1) sum += __shfl_xor(sum, off);
        lrun[mi][r] = lrun[mi][r] * alpha + sum;
#pragma unroll
        for (int f = 0; f < 4; ++f) acc[mi][f][r] *= alpha;
#pragma unroll
        for (int ni = 0; ni < 4; ++ni)
          Ps[w * 32 + mi * 16 + lk * 4 + r][ni * 16 + lr] = f2bf(s[mi][ni][r]);
      }
    }

    // ---- O += P V ----
    bf16x8 vb[4][2];
#pragma unroll
    for (int f = 0; f < 4; ++f)
#pragma unroll
      for (int kk = 0; kk < 2; ++kk)
        vb[f][kk] = __builtin_bit_cast(bf16x8, *(const u16x8*)(&Vt[f * 16 + lr][kk * 32 + lk * 8]));
    bf16x8 pa[2][2];
#pragma unroll
    for (int mi = 0; mi < 2; ++mi)
#pragma unroll
      for (int kk = 0; kk < 2; ++kk)
        pa[mi][kk] = __builtin_bit_cast(bf16x8, *(const u16x8*)(&Ps[w * 32 + mi * 16 + lr][kk * 32 + lk * 8]));
#pragma unroll
    for (int mi = 0; mi < 2; ++mi)
#pragma unroll
      for (int f = 0; f < 4; ++f) {
        acc[mi][f] = __builtin_amdgcn_mfma_f32_16x16x32_bf16(pa[mi][0], vb[f][0], acc[mi][f], 0, 0, 0);
        acc[mi][f] = __builtin_amdgcn_mfma_f32_16x16x32_bf16(pa[mi][1], vb[f][1], acc[mi][f], 0, 0, 0);
      }
  }

  // ---- normalize + store bf16 ----
#pragma unroll
  for (int mi = 0; mi < 2; ++mi)
#pragma unroll
    for (int f = 0; f < 4; ++f)
#pragma unroll
      for (int r = 0; r < 4; ++r) {
        const int row = q0 + mi * 16 + lk * 4 + r;
        const int col = hoff + f * 16 + lr;
        Ao[(size_t)(b * SEQ + row) * D_MODEL + col] = f2bf(acc[mi][f][r] / lrun[mi][r]);
      }
}

// ---------------- launch ----------------
// d_ws layout (shorts): xb[nMD] | qp[nMD] | kp[nMD] | vp[nMD] | wb[nDD]
// peak ~69 MB. attn output aliases xb (dead after V projection).
extern "C" void kernel_launch(void* const* d_in, const int* in_sizes, int n_in,
                              void* d_out, int out_size, void* d_ws, size_t ws_size,
                              hipStream_t stream) {
  const float* q  = (const float*)d_in[0];
  const float* k  = (const float*)d_in[1];
  const float* v  = (const float*)d_in[2];
  const float* wq = (const float*)d_in[3];
  const float* bq = (const float*)d_in[4];
  const float* wk = (const float*)d_in[5];
  const float* bk = (const float*)d_in[6];
  const float* wv = (const float*)d_in[7];
  const float* bv = (const float*)d_in[8];
  const float* wo = (const float*)d_in[9];
  const float* bo = (const float*)d_in[10];
  float* out = (float*)d_out;

  const int M = BATCH * SEQ;            // 8192
  const int D = D_MODEL;                // 1024
  const size_t nMD = (size_t)M * D;     // 8,388,608
  const size_t nDD = (size_t)D * D;     // 1,048,576

  unsigned short* ws = (unsigned short*)d_ws;
  unsigned short* xb = ws;              // bf16 input (reused q->k->v), then attn out
  unsigned short* qp = xb + nMD;
  unsigned short* kp = qp + nMD;
  unsigned short* vp = kp + nMD;
  unsigned short* wb = vp + nMD;        // bf16 weight (reused wq->wk->wv->wo)
  unsigned short* ao = xb;

  dim3 gg(512);                         // (N/128=8) x (M/128=64)

  cvtk<<<256,  256, 0, stream>>>(wq, wb, (int)nDD);
  cvtk<<<2048, 256, 0, stream>>>(q,  xb, (int)nMD);
  gemm_bt<0><<<gg, 256, 0, stream>>>(xb, wb, bq, qp, nullptr, M, D, D);

  cvtk<<<256,  256, 0, stream>>>(wk, wb, (int)nDD);
  cvtk<<<2048, 256, 0, stream>>>(k,  xb, (int)nMD);
  gemm_bt<0><<<gg, 256, 0, stream>>>(xb, wb, bk, kp, nullptr, M, D, D);

  cvtk<<<256,  256, 0, stream>>>(wv, wb, (int)nDD);
  cvtk<<<2048, 256, 0, stream>>>(v,  xb, (int)nMD);
  gemm_bt<0><<<gg, 256, 0, stream>>>(xb, wb, bv, vp, nullptr, M, D, D);

  attn_fwd<<<dim3(1024), 256, 0, stream>>>(qp, kp, vp, ao);

  cvtk<<<256, 256, 0, stream>>>(wo, wb, (int)nDD);
  gemm_bt<1><<<gg, 256, 0, stream>>>(ao, wb, bo, nullptr, out, M, D, D);
}

// Round 6
// 438.980 us; speedup vs baseline: 1.3679x; 1.3679x over previous
//
#include <hip/hip_runtime.h>
#include <hip/hip_bf16.h>
#include <cstdint>
#include <cstddef>

#define D_MODEL 1024
#define N_HEAD  16
#define DH      64
#define SEQ     2048
#define BATCH   4

typedef __attribute__((ext_vector_type(8))) __bf16 bf16x8;
typedef __attribute__((ext_vector_type(8))) unsigned short u16x8;
typedef __attribute__((ext_vector_type(4))) unsigned short u16x4;
typedef __attribute__((ext_vector_type(4))) float f32x4;

#define AS3 __attribute__((address_space(3)))

static __device__ __forceinline__ unsigned short f2bf(float f) {
  unsigned int u = __builtin_bit_cast(unsigned int, f);
  u += 0x7fffu + ((u >> 16) & 1u);   // round-to-nearest-even
  return (unsigned short)(u >> 16);
}

static __device__ __forceinline__ float fexp2(float x) {
#if __has_builtin(__builtin_amdgcn_exp2f)
  return __builtin_amdgcn_exp2f(x);
#else
  return exp2f(x);
#endif
}

static __device__ __forceinline__ void gll16(const unsigned short* g, unsigned short* l) {
  __builtin_amdgcn_global_load_lds((const __attribute__((address_space(1))) void*)g,
                                   (AS3 void*)l, 16, 0, 0);
}

// bijective XCD swizzle (nwg % 8 == 0)
static __device__ __forceinline__ int xcd_swz(int bid, int nwg) {
  const int cpx = nwg >> 3;
  return (bid & 7) * cpx + (bid >> 3);
}

// ---------------- fp32 -> bf16 convert ----------------
__global__ void cvtk(const float* __restrict__ in, unsigned short* __restrict__ out, int n) {
  int stride = gridDim.x * blockDim.x;
  for (int i = blockIdx.x * blockDim.x + threadIdx.x; i * 8 < n; i += stride) {
    float4 a = *(const float4*)(in + (size_t)i * 8);
    float4 b = *(const float4*)(in + (size_t)i * 8 + 4);
    u16x8 o;
    o[0] = f2bf(a.x); o[1] = f2bf(a.y); o[2] = f2bf(a.z); o[3] = f2bf(a.w);
    o[4] = f2bf(b.x); o[5] = f2bf(b.y); o[6] = f2bf(b.z); o[7] = f2bf(b.w);
    *(u16x8*)(out + (size_t)i * 8) = o;
  }
}

// ---------------- NT GEMM, 2-phase double-buffered ----------------
template<int OUTF32>
__global__ __launch_bounds__(256) void gemm_bt(
    const unsigned short* __restrict__ A,
    const unsigned short* __restrict__ B,
    const float* __restrict__ bias,
    unsigned short* __restrict__ Cb, float* __restrict__ Cf,
    int M, int N, int K)
{
  alignas(16) __shared__ unsigned short As[2][128 * 32];
  alignas(16) __shared__ unsigned short Bs[2][128 * 32];
  const int t  = threadIdx.x;
  const int w  = t >> 6, l = t & 63;
  const int lr = l & 15, lk = l >> 4;

  const int nbx = N >> 7;
  const int swz = xcd_swz(blockIdx.x, gridDim.x);
  const int bn0 = (swz % nbx) * 128, bm0 = (swz / nbx) * 128;
  const int wm = (w >> 1) * 64, wn = (w & 1) * 64;

  f32x4 acc[4][4] = {};
  const int NT = K >> 5;   // 32 (power of 2)

  auto stage = [&](int kt) {
    const int buf = kt & 1;
    const int k0 = kt << 5;
#pragma unroll
    for (int i = 0; i < 2; ++i) {
      int c = i * 256 + t;
      int row = c >> 2, ko = (c & 3) << 3;
      int ub = __builtin_amdgcn_readfirstlane((c & ~63) * 8);
      gll16(A + (size_t)(bm0 + row) * K + k0 + ko, &As[buf][ub]);
      gll16(B + (size_t)(bn0 + row) * K + k0 + ko, &Bs[buf][ub]);
    }
  };

  stage(0);
  asm volatile("s_waitcnt vmcnt(0)" ::: "memory");
  __syncthreads();

  for (int kt = 0; kt < NT; ++kt) {
    const int cur = kt & 1;
    stage((kt + 1) & (NT - 1));          // into buf cur^1; flies during compute
    bf16x8 af[4], bfr[4];
#pragma unroll
    for (int i = 0; i < 4; ++i) {
      af[i]  = __builtin_bit_cast(bf16x8, *(const u16x8*)&As[cur][(wm + i * 16 + lr) * 32 + lk * 8]);
      bfr[i] = __builtin_bit_cast(bf16x8, *(const u16x8*)&Bs[cur][(wn + i * 16 + lr) * 32 + lk * 8]);
    }
#pragma unroll
    for (int mi = 0; mi < 4; ++mi)
#pragma unroll
      for (int ni = 0; ni < 4; ++ni)
        acc[mi][ni] = __builtin_amdgcn_mfma_f32_16x16x32_bf16(af[mi], bfr[ni], acc[mi][ni], 0, 0, 0);
    asm volatile("s_waitcnt vmcnt(0)" ::: "memory");
    __syncthreads();
  }

  float bv[4];
#pragma unroll
  for (int ni = 0; ni < 4; ++ni) bv[ni] = bias[bn0 + wn + ni * 16 + lr];
#pragma unroll
  for (int mi = 0; mi < 4; ++mi)
#pragma unroll
    for (int ni = 0; ni < 4; ++ni) {
      const int col = bn0 + wn + ni * 16 + lr;
#pragma unroll
      for (int r = 0; r < 4; ++r) {
        const int row = bm0 + wm + mi * 16 + lk * 4 + r;
        float v = acc[mi][ni][r] + bv[ni];
        if (OUTF32) Cf[(size_t)row * N + col] = v;
        else        Cb[(size_t)row * N + col] = f2bf(v);
      }
    }
}

// ---------------- flash attention fwd (swapped-QK, reg-transposed V, dbuf) ----
// grid 1024 XCD-swizzled; 256 thr = 4 waves x 32 q-rows. KV tile 64.
// K LDS row-major [j][64], swizzled: elem(j,d) = j*64 + 8*((d>>3)^(j&7)) + (d&7)
//   (swizzle folded into the global source column; LDS dest linear; rule 21)
// V LDS d-major [d][64(j)], swizzled: elem(d,j) = d*64 + 8*((j>>3)^(d&7)^(d>>3)) + (j&7)
//   written transposed from registers (16 scalar b16 writes/thread, conflict-free)
// Ps per-wave [32(q)][64(j)], swizzled like K with q as the row.
__global__ __launch_bounds__(256) void attn_fwd(
    const unsigned short* __restrict__ Qp,
    const unsigned short* __restrict__ Kp,
    const unsigned short* __restrict__ Vp,
    unsigned short* __restrict__ Ao)
{
  alignas(16) __shared__ unsigned short Ks[2][64 * 64];
  alignas(16) __shared__ unsigned short Vt[2][64 * 64];
  alignas(16) __shared__ unsigned short Ps[4][32 * 64];

  const int t = threadIdx.x, w = t >> 6, l = t & 63;
  const int lr = l & 15, lk = l >> 4;
  const int swz = xcd_swz(blockIdx.x, gridDim.x);
  const int qt = swz & 15, h = (swz >> 4) & 15, b = swz >> 8;
  const int hoff = h * DH;
  const int q0 = qt * 128 + w * 32;

  // Q as B-fragments (resident): B[col=q=mi*16+lr][k=d=kk*32+lk*8+jj]
  bf16x8 qf[2][2];
#pragma unroll
  for (int mi = 0; mi < 2; ++mi)
#pragma unroll
    for (int kk = 0; kk < 2; ++kk)
      qf[mi][kk] = __builtin_bit_cast(bf16x8,
        *(const u16x8*)(Qp + (size_t)(b * SEQ + q0 + mi * 16 + lr) * D_MODEL + hoff + kk * 32 + lk * 8));

  f32x4 acc[2][4] = {};
  float m2[2]   = {-1e30f, -1e30f};   // running max, base-2 domain
  float lrun[2] = {0.f, 0.f};
  const float C1  = 0.18033688f;      // 0.125 * log2(e)
  const float THR = 11.541560f;       // 8 * log2(e)

  // V staging thread geometry (per 16B chunk cc): row j = cc>>3, d0 = (cc&7)*8
  auto stageK = [&](int jt) {
    const int buf = jt & 1;
    const size_t rbase = (size_t)b * SEQ + (size_t)jt * 64;
#pragma unroll
    for (int i = 0; i < 2; ++i) {
      const int c = i * 256 + t;
      const int ub = __builtin_amdgcn_readfirstlane((c & ~63) * 8);
      const int j = c >> 3, d = 8 * ((c & 7) ^ (j & 7));   // pre-swizzled global col
      gll16(Kp + (rbase + j) * D_MODEL + hoff + d, &Ks[buf][ub]);
    }
  };
  u16x8 vreg[2];
  auto loadV = [&](int jt) {
    const size_t rbase = (size_t)b * SEQ + (size_t)jt * 64;
#pragma unroll
    for (int i = 0; i < 2; ++i) {
      const int cc = i * 256 + t;
      vreg[i] = *(const u16x8*)(Vp + (rbase + (cc >> 3)) * D_MODEL + hoff + (cc & 7) * 8);
    }
  };
  auto writeV = [&](int buf) {
#pragma unroll
    for (int i = 0; i < 2; ++i) {
      const int cc = i * 256 + t;
      const int j = cc >> 3, x = cc & 7;   // d0 = 8x; holds V[j][8x..8x+7]
#pragma unroll
      for (int m = 0; m < 8; ++m) {
        const int d = 8 * x + m;
        Vt[buf][d * 64 + 8 * ((j >> 3) ^ m ^ x) + (j & 7)] = vreg[i][m];
      }
    }
  };

  stageK(0);
  loadV(0);
  asm volatile("s_waitcnt vmcnt(0)" ::: "memory");
  writeV(0);
  __syncthreads();

  for (int jt = 0; jt < SEQ / 64; ++jt) {
    const int cur = jt & 1;
    const int nxt = (jt + 1) & (SEQ / 64 - 1);
    stageK(nxt);        // K tile jt+1 -> Ks[cur^1], flies during compute
    loadV(nxt);         // V tile jt+1 -> registers, flies during compute

    // K as A-fragments from swizzled LDS: A[row=j][k=d]
    bf16x8 kb[4][2];
#pragma unroll
    for (int ni = 0; ni < 4; ++ni)
#pragma unroll
      for (int kk = 0; kk < 2; ++kk) {
        const int j = ni * 16 + lr;
        const int off = j * 64 + 8 * ((4 * kk + lk) ^ (j & 7));
        kb[ni][kk] = __builtin_bit_cast(bf16x8, *(const u16x8*)&Ks[cur][off]);
      }

    // S^T = K Q^T: lane holds S[q = mi*16+lr][j = ni*16 + 4*lk + r]
    f32x4 s[2][4];
#pragma unroll
    for (int mi = 0; mi < 2; ++mi)
#pragma unroll
      for (int ni = 0; ni < 4; ++ni) {
        f32x4 z = {};
        z = __builtin_amdgcn_mfma_f32_16x16x32_bf16(kb[ni][0], qf[mi][0], z, 0, 0, 0);
        z = __builtin_amdgcn_mfma_f32_16x16x32_bf16(kb[ni][1], qf[mi][1], z, 0, 0, 0);
        s[mi][ni] = z;
      }

    // online softmax: per-lane q-column; reduce over the 4 lanes sharing lr
#pragma unroll
    for (int mi = 0; mi < 2; ++mi) {
      float vmax = s[mi][0][0];
#pragma unroll
      for (int ni = 0; ni < 4; ++ni)
#pragma unroll
        for (int r = 0; r < 4; ++r) vmax = fmaxf(vmax, s[mi][ni][r]);
      vmax = fmaxf(vmax, __shfl_xor(vmax, 16));
      vmax = fmaxf(vmax, __shfl_xor(vmax, 32));
      const float sm2 = vmax * C1;
      if (!__all(sm2 - m2[mi] <= THR)) {          // T13 defer-max
        const float mnew  = fmaxf(m2[mi], sm2);
        const float alpha = fexp2(m2[mi] - mnew);
        m2[mi] = mnew;
        lrun[mi] *= alpha;
#pragma unroll
        for (int r = 0; r < 4; ++r) {
          const float ar = __shfl(alpha, (l & 48) | (((l >> 4) & 3) << 2) | r);
#pragma unroll
          for (int f = 0; f < 4; ++f) acc[mi][f][r] *= ar;
        }
      }
      float sum = 0.f;
      u16x4 pk[4];
#pragma unroll
      for (int ni = 0; ni < 4; ++ni)
#pragma unroll
        for (int r = 0; r < 4; ++r) {
          const float p = fexp2(fmaf(s[mi][ni][r], C1, -m2[mi]));
          sum += p;
          pk[ni][r] = f2bf(p);
        }
      sum += __shfl_xor(sum, 16);
      sum += __shfl_xor(sum, 32);
      lrun[mi] += sum;
      const int q = mi * 16 + lr;
#pragma unroll
      for (int nj = 0; nj < 4; ++nj) {   // j0 = nj*16 + 4*lk, 4 consecutive j
        const int off = q * 64 + (((nj * 32 + lk * 8) ^ ((q & 7) << 4)) >> 1);
        *(u16x4*)&Ps[w][off] = pk[nj];
      }
    }

    // P as A-fragments: A[row=q][k=j]
    bf16x8 pa[2][2];
#pragma unroll
    for (int mi = 0; mi < 2; ++mi)
#pragma unroll
      for (int kk = 0; kk < 2; ++kk) {
        const int q = mi * 16 + lr;
        const int off = q * 64 + 8 * ((4 * kk + lk) ^ (q & 7));
        pa[mi][kk] = __builtin_bit_cast(bf16x8, *(const u16x8*)&Ps[w][off]);
      }

    // V as B-fragments from transposed LDS: B[k=j][col=d]
    bf16x8 vb[4][2];
#pragma unroll
    for (int f = 0; f < 4; ++f)
#pragma unroll
      for (int kk = 0; kk < 2; ++kk) {
        const int d = 16 * f + lr;
        const int off = d * 64 + 8 * ((4 * kk + lk) ^ (lr & 7) ^ ((2 * f + (lr >> 3)) & 7));
        vb[f][kk] = __builtin_bit_cast(bf16x8, *(const u16x8*)&Vt[cur][off]);
      }

    // O += P V  (acc[mi][f][r] = O[q = mi*16+4*lk+r][d = 16*f+lr])
#pragma unroll
    for (int mi = 0; mi < 2; ++mi)
#pragma unroll
      for (int f = 0; f < 4; ++f) {
        acc[mi][f] = __builtin_amdgcn_mfma_f32_16x16x32_bf16(pa[mi][0], vb[f][0], acc[mi][f], 0, 0, 0);
        acc[mi][f] = __builtin_amdgcn_mfma_f32_16x16x32_bf16(pa[mi][1], vb[f][1], acc[mi][f], 0, 0, 0);
      }

    asm volatile("s_waitcnt vmcnt(0)" ::: "memory");   // K-lds + V-reg loads done
    writeV(cur ^ 1);                                   // safe: readers gone since last barrier
    __syncthreads();
  }

  // normalize + store
#pragma unroll
  for (int mi = 0; mi < 2; ++mi)
#pragma unroll
    for (int r = 0; r < 4; ++r) {
      const float lr_r = __shfl(lrun[mi], (l & 48) | (((l >> 4) & 3) << 2) | r);
      const float inv = 1.0f / lr_r;
      const int row = q0 + mi * 16 + (l >> 4) * 4 + r;
#pragma unroll
      for (int f = 0; f < 4; ++f)
        Ao[(size_t)(b * SEQ + row) * D_MODEL + hoff + f * 16 + lr] = f2bf(acc[mi][f][r] * inv);
    }
}

// ---------------- launch ----------------
extern "C" void kernel_launch(void* const* d_in, const int* in_sizes, int n_in,
                              void* d_out, int out_size, void* d_ws, size_t ws_size,
                              hipStream_t stream) {
  const float* q  = (const float*)d_in[0];
  const float* k  = (const float*)d_in[1];
  const float* v  = (const float*)d_in[2];
  const float* wq = (const float*)d_in[3];
  const float* bq = (const float*)d_in[4];
  const float* wk = (const float*)d_in[5];
  const float* bk = (const float*)d_in[6];
  const float* wv = (const float*)d_in[7];
  const float* bv = (const float*)d_in[8];
  const float* wo = (const float*)d_in[9];
  const float* bo = (const float*)d_in[10];
  float* out = (float*)d_out;

  const int M = BATCH * SEQ;            // 8192
  const int D = D_MODEL;                // 1024
  const size_t nMD = (size_t)M * D;
  const size_t nDD = (size_t)D * D;

  unsigned short* ws = (unsigned short*)d_ws;
  unsigned short* xb = ws;              // bf16 input (reused), then attn out
  unsigned short* qp = xb + nMD;
  unsigned short* kp = qp + nMD;
  unsigned short* vp = kp + nMD;
  unsigned short* wb = vp + nMD;        // bf16 weight (reused)
  unsigned short* ao = xb;

  dim3 gg(512);

  cvtk<<<256,  256, 0, stream>>>(wq, wb, (int)nDD);
  cvtk<<<2048, 256, 0, stream>>>(q,  xb, (int)nMD);
  gemm_bt<0><<<gg, 256, 0, stream>>>(xb, wb, bq, qp, nullptr, M, D, D);

  cvtk<<<256,  256, 0, stream>>>(wk, wb, (int)nDD);
  cvtk<<<2048, 256, 0, stream>>>(k,  xb, (int)nMD);
  gemm_bt<0><<<gg, 256, 0, stream>>>(xb, wb, bk, kp, nullptr, M, D, D);

  cvtk<<<256,  256, 0, stream>>>(wv, wb, (int)nDD);
  cvtk<<<2048, 256, 0, stream>>>(v,  xb, (int)nMD);
  gemm_bt<0><<<gg, 256, 0, stream>>>(xb, wb, bv, vp, nullptr, M, D, D);

  attn_fwd<<<dim3(1024), 256, 0, stream>>>(qp, kp, vp, ao);

  cvtk<<<256, 256, 0, stream>>>(wo, wb, (int)nDD);
  gemm_bt<1><<<gg, 256, 0, stream>>>(ao, wb, bo, nullptr, out, M, D, D);
}

// Round 7
// 410.784 us; speedup vs baseline: 1.4618x; 1.0686x over previous
//
#include <hip/hip_runtime.h>
#include <hip/hip_bf16.h>
#include <cstdint>
#include <cstddef>

#define D_MODEL 1024
#define N_HEAD  16
#define DH      64
#define SEQ     2048
#define BATCH   4

typedef __attribute__((ext_vector_type(8))) __bf16 bf16x8;
typedef __attribute__((ext_vector_type(8))) unsigned short u16x8;
typedef __attribute__((ext_vector_type(4))) unsigned short u16x4;
typedef __attribute__((ext_vector_type(2))) unsigned int u32x2;
typedef __attribute__((ext_vector_type(4))) float f32x4;

#define AS3 __attribute__((address_space(3)))

static __device__ __forceinline__ unsigned short f2bf(float f) {
  unsigned int u = __builtin_bit_cast(unsigned int, f);
  u += 0x7fffu + ((u >> 16) & 1u);   // round-to-nearest-even
  return (unsigned short)(u >> 16);
}

static __device__ __forceinline__ float fexp2(float x) {
#if __has_builtin(__builtin_amdgcn_exp2f)
  return __builtin_amdgcn_exp2f(x);
#else
  return exp2f(x);
#endif
}

static __device__ __forceinline__ void gll16(const unsigned short* g, unsigned short* l) {
  __builtin_amdgcn_global_load_lds((const __attribute__((address_space(1))) void*)g,
                                   (AS3 void*)l, 16, 0, 0);
}

// bijective XCD swizzle (nwg % 8 == 0)
static __device__ __forceinline__ int xcd_swz(int bid, int nwg) {
  const int cpx = nwg >> 3;
  return (bid & 7) * cpx + (bid >> 3);
}

// ---------------- fp32 -> bf16 convert, up to 3 segments, 2048 elems/block ----
__global__ void cvtseg(const float* __restrict__ i0, unsigned short* __restrict__ o0, int nb0,
                       const float* __restrict__ i1, unsigned short* __restrict__ o1, int nb1,
                       const float* __restrict__ i2, unsigned short* __restrict__ o2) {
  int bb = blockIdx.x;
  const float* in; unsigned short* out;
  if (bb < nb0)            { in = i0; out = o0; }
  else if (bb < nb0 + nb1) { in = i1; out = o1; bb -= nb0; }
  else                     { in = i2; out = o2; bb -= nb0 + nb1; }
  const size_t base = (size_t)bb * 2048 + (size_t)threadIdx.x * 8;
  float4 a = *(const float4*)(in + base);
  float4 b = *(const float4*)(in + base + 4);
  u16x8 o;
  o[0] = f2bf(a.x); o[1] = f2bf(a.y); o[2] = f2bf(a.z); o[3] = f2bf(a.w);
  o[4] = f2bf(b.x); o[5] = f2bf(b.y); o[6] = f2bf(b.z); o[7] = f2bf(b.w);
  *(u16x8*)(out + base) = o;
}

// ---------------- NT GEMM, BK=64, 2-phase dbuf, XOR-swizzled LDS ----------------
// LDS tile [128][64], chunk x (8 elems) of row stored at slot x^(row&7)
// (swizzle pre-applied on the GLOBAL source column; LDS dest linear — rule 21)
template<int OUTF32>
__global__ __launch_bounds__(256) void gemm_bt(
    const unsigned short* __restrict__ A,
    const unsigned short* __restrict__ B,
    const float* __restrict__ bias,
    unsigned short* __restrict__ Cb, float* __restrict__ Cf,
    int M, int N, int K)
{
  alignas(16) __shared__ unsigned short As[2][128 * 64];
  alignas(16) __shared__ unsigned short Bs[2][128 * 64];
  const int t  = threadIdx.x;
  const int w  = t >> 6, l = t & 63;
  const int lr = l & 15, lk = l >> 4;

  const int nbx = N >> 7;
  const int swz = xcd_swz(blockIdx.x, gridDim.x);
  const int bn0 = (swz % nbx) * 128, bm0 = (swz / nbx) * 128;
  const int wm = (w >> 1) * 64, wn = (w & 1) * 64;

  f32x4 acc[4][4] = {};
  const int NT = K >> 6;   // 16 (power of 2)

  auto stage = [&](int kt) {
    const int buf = kt & 1;
    const int k0 = kt << 6;
#pragma unroll
    for (int i = 0; i < 4; ++i) {
      int c = i * 256 + t;
      int row = c >> 3, x = c & 7;
      int ko = 8 * (x ^ (row & 7));    // pre-swizzled source column
      int ub = __builtin_amdgcn_readfirstlane((c & ~63) * 8);
      gll16(A + (size_t)(bm0 + row) * K + k0 + ko, &As[buf][ub]);
      gll16(B + (size_t)(bn0 + row) * K + k0 + ko, &Bs[buf][ub]);
    }
  };

  stage(0);
  asm volatile("s_waitcnt vmcnt(0)" ::: "memory");
  __syncthreads();

  for (int kt = 0; kt < NT; ++kt) {
    const int cur = kt & 1;
    stage((kt + 1) & (NT - 1));          // into buf cur^1; flies during compute
    bf16x8 af[4][2], bfr[4][2];
#pragma unroll
    for (int i = 0; i < 4; ++i)
#pragma unroll
      for (int kk = 0; kk < 2; ++kk) {
        const int ra = wm + i * 16 + lr, rb = wn + i * 16 + lr;
        af[i][kk]  = __builtin_bit_cast(bf16x8,
          *(const u16x8*)&As[cur][ra * 64 + 8 * ((4 * kk + lk) ^ (ra & 7))]);
        bfr[i][kk] = __builtin_bit_cast(bf16x8,
          *(const u16x8*)&Bs[cur][rb * 64 + 8 * ((4 * kk + lk) ^ (rb & 7))]);
      }
#pragma unroll
    for (int kk = 0; kk < 2; ++kk)
#pragma unroll
      for (int mi = 0; mi < 4; ++mi)
#pragma unroll
        for (int ni = 0; ni < 4; ++ni)
          acc[mi][ni] = __builtin_amdgcn_mfma_f32_16x16x32_bf16(af[mi][kk], bfr[ni][kk], acc[mi][ni], 0, 0, 0);
    asm volatile("s_waitcnt vmcnt(0)" ::: "memory");
    __syncthreads();
  }

  float bv[4];
#pragma unroll
  for (int ni = 0; ni < 4; ++ni) bv[ni] = bias[bn0 + wn + ni * 16 + lr];
#pragma unroll
  for (int mi = 0; mi < 4; ++mi)
#pragma unroll
    for (int ni = 0; ni < 4; ++ni) {
      const int col = bn0 + wn + ni * 16 + lr;
#pragma unroll
      for (int r = 0; r < 4; ++r) {
        const int row = bm0 + wm + mi * 16 + lk * 4 + r;
        float v = acc[mi][ni][r] + bv[ni];
        if (OUTF32) Cf[(size_t)row * N + col] = v;
        else        Cb[(size_t)row * N + col] = f2bf(v);
      }
    }
}

// ---------------- flash attention fwd (swapped-QK, reg-transposed V, dbuf) ----
__global__ __launch_bounds__(256) void attn_fwd(
    const unsigned short* __restrict__ Qp,
    const unsigned short* __restrict__ Kp,
    const unsigned short* __restrict__ Vp,
    unsigned short* __restrict__ Ao)
{
  alignas(16) __shared__ unsigned short Ks[2][64 * 64];
  alignas(16) __shared__ unsigned short Vt[2][64 * 64];
  alignas(16) __shared__ unsigned short Ps[4][32 * 64];

  const int t = threadIdx.x, w = t >> 6, l = t & 63;
  const int lr = l & 15, lk = l >> 4;
  const int swz = xcd_swz(blockIdx.x, gridDim.x);
  const int qt = swz & 15, h = (swz >> 4) & 15, b = swz >> 8;
  const int hoff = h * DH;
  const int q0 = qt * 128 + w * 32;

  // Q as B-fragments (resident): B[col=q=mi*16+lr][k=d=kk*32+lk*8+jj]
  bf16x8 qf[2][2];
#pragma unroll
  for (int mi = 0; mi < 2; ++mi)
#pragma unroll
    for (int kk = 0; kk < 2; ++kk)
      qf[mi][kk] = __builtin_bit_cast(bf16x8,
        *(const u16x8*)(Qp + (size_t)(b * SEQ + q0 + mi * 16 + lr) * D_MODEL + hoff + kk * 32 + lk * 8));

  f32x4 acc[2][4] = {};
  float m2[2]   = {-1e30f, -1e30f};   // running max, base-2 domain
  float lrun[2] = {0.f, 0.f};
  const float C1  = 0.18033688f;      // 0.125 * log2(e)
  const float THR = 11.541560f;       // 8 * log2(e)

  auto stageK = [&](int jt) {
    const int buf = jt & 1;
    const size_t rbase = (size_t)b * SEQ + (size_t)jt * 64;
#pragma unroll
    for (int i = 0; i < 2; ++i) {
      const int c = i * 256 + t;
      const int ub = __builtin_amdgcn_readfirstlane((c & ~63) * 8);
      const int j = c >> 3, d = 8 * ((c & 7) ^ (j & 7));   // pre-swizzled global col
      gll16(Kp + (rbase + j) * D_MODEL + hoff + d, &Ks[buf][ub]);
    }
  };
  u16x8 vreg[2];
  auto loadV = [&](int jt) {
    const size_t rbase = (size_t)b * SEQ + (size_t)jt * 64;
#pragma unroll
    for (int i = 0; i < 2; ++i) {
      const int cc = i * 256 + t;
      vreg[i] = *(const u16x8*)(Vp + (rbase + (cc >> 3)) * D_MODEL + hoff + (cc & 7) * 8);
    }
  };
  auto writeV = [&](int buf) {
#pragma unroll
    for (int i = 0; i < 2; ++i) {
      const int cc = i * 256 + t;
      const int j = cc >> 3, x = cc & 7;   // holds V[j][8x..8x+7]
#pragma unroll
      for (int m = 0; m < 8; ++m) {
        const int d = 8 * x + m;
        Vt[buf][d * 64 + 8 * ((j >> 3) ^ m ^ x) + (j & 7)] = vreg[i][m];
      }
    }
  };

  stageK(0);
  loadV(0);
  asm volatile("s_waitcnt vmcnt(0)" ::: "memory");
  writeV(0);
  __syncthreads();

  for (int jt = 0; jt < SEQ / 64; ++jt) {
    const int cur = jt & 1;
    const int nxt = (jt + 1) & (SEQ / 64 - 1);
    stageK(nxt);        // K tile jt+1 -> Ks[cur^1], flies during compute
    loadV(nxt);         // V tile jt+1 -> registers, flies during compute

    // K as A-fragments from swizzled LDS: A[row=j][k=d]
    bf16x8 kb[4][2];
#pragma unroll
    for (int ni = 0; ni < 4; ++ni)
#pragma unroll
      for (int kk = 0; kk < 2; ++kk) {
        const int j = ni * 16 + lr;
        const int off = j * 64 + 8 * ((4 * kk + lk) ^ (j & 7));
        kb[ni][kk] = __builtin_bit_cast(bf16x8, *(const u16x8*)&Ks[cur][off]);
      }

    // S^T = K Q^T: lane holds S[q = mi*16+lr][j = ni*16 + 4*lk + r]
    f32x4 s[2][4];
    __builtin_amdgcn_s_setprio(1);
#pragma unroll
    for (int mi = 0; mi < 2; ++mi)
#pragma unroll
      for (int ni = 0; ni < 4; ++ni) {
        f32x4 z = {};
        z = __builtin_amdgcn_mfma_f32_16x16x32_bf16(kb[ni][0], qf[mi][0], z, 0, 0, 0);
        z = __builtin_amdgcn_mfma_f32_16x16x32_bf16(kb[ni][1], qf[mi][1], z, 0, 0, 0);
        s[mi][ni] = z;
      }
    __builtin_amdgcn_s_setprio(0);

    // online softmax: per-lane q-column; reduce over the 4 lanes sharing lr
#pragma unroll
    for (int mi = 0; mi < 2; ++mi) {
      float vmax = s[mi][0][0];
#pragma unroll
      for (int ni = 0; ni < 4; ++ni)
#pragma unroll
        for (int r = 0; r < 4; ++r) vmax = fmaxf(vmax, s[mi][ni][r]);
      vmax = fmaxf(vmax, __shfl_xor(vmax, 16));
      vmax = fmaxf(vmax, __shfl_xor(vmax, 32));
      const float sm2 = vmax * C1;
      if (!__all(sm2 - m2[mi] <= THR)) {          // T13 defer-max
        const float mnew  = fmaxf(m2[mi], sm2);
        const float alpha = fexp2(m2[mi] - mnew);
        m2[mi] = mnew;
        lrun[mi] *= alpha;
#pragma unroll
        for (int r = 0; r < 4; ++r) {
          const float ar = __shfl(alpha, (l & 48) | (((l >> 4) & 3) << 2) | r);
#pragma unroll
          for (int f = 0; f < 4; ++f) acc[mi][f][r] *= ar;
        }
      }
      float sum = 0.f;
      unsigned int pw[4][2];
#pragma unroll
      for (int ni = 0; ni < 4; ++ni) {
        float p0 = fexp2(fmaf(s[mi][ni][0], C1, -m2[mi]));
        float p1 = fexp2(fmaf(s[mi][ni][1], C1, -m2[mi]));
        float p2 = fexp2(fmaf(s[mi][ni][2], C1, -m2[mi]));
        float p3 = fexp2(fmaf(s[mi][ni][3], C1, -m2[mi]));
        sum += (p0 + p1) + (p2 + p3);
        asm("v_cvt_pk_bf16_f32 %0, %1, %2" : "=v"(pw[ni][0]) : "v"(p0), "v"(p1));
        asm("v_cvt_pk_bf16_f32 %0, %1, %2" : "=v"(pw[ni][1]) : "v"(p2), "v"(p3));
      }
      sum += __shfl_xor(sum, 16);
      sum += __shfl_xor(sum, 32);
      lrun[mi] += sum;
      const int q = mi * 16 + lr;
#pragma unroll
      for (int nj = 0; nj < 4; ++nj) {   // j0 = nj*16 + 4*lk, 4 consecutive j
        const int off = q * 64 + (((nj * 32 + lk * 8) ^ ((q & 7) << 4)) >> 1);
        u32x2 pv2 = {pw[nj][0], pw[nj][1]};
        *(u32x2*)&Ps[w][off] = pv2;
      }
    }

    // P as A-fragments: A[row=q][k=j]
    bf16x8 pa[2][2];
#pragma unroll
    for (int mi = 0; mi < 2; ++mi)
#pragma unroll
      for (int kk = 0; kk < 2; ++kk) {
        const int q = mi * 16 + lr;
        const int off = q * 64 + 8 * ((4 * kk + lk) ^ (q & 7));
        pa[mi][kk] = __builtin_bit_cast(bf16x8, *(const u16x8*)&Ps[w][off]);
      }

    // V as B-fragments from transposed LDS: B[k=j][col=d]
    bf16x8 vb[4][2];
#pragma unroll
    for (int f = 0; f < 4; ++f)
#pragma unroll
      for (int kk = 0; kk < 2; ++kk) {
        const int d = 16 * f + lr;
        const int off = d * 64 + 8 * ((4 * kk + lk) ^ (lr & 7) ^ ((2 * f + (lr >> 3)) & 7));
        vb[f][kk] = __builtin_bit_cast(bf16x8, *(const u16x8*)&Vt[cur][off]);
      }

    // O += P V  (acc[mi][f][r] = O[q = mi*16+4*lk+r][d = 16*f+lr])
    __builtin_amdgcn_s_setprio(1);
#pragma unroll
    for (int mi = 0; mi < 2; ++mi)
#pragma unroll
      for (int f = 0; f < 4; ++f) {
        acc[mi][f] = __builtin_amdgcn_mfma_f32_16x16x32_bf16(pa[mi][0], vb[f][0], acc[mi][f], 0, 0, 0);
        acc[mi][f] = __builtin_amdgcn_mfma_f32_16x16x32_bf16(pa[mi][1], vb[f][1], acc[mi][f], 0, 0, 0);
      }
    __builtin_amdgcn_s_setprio(0);

    asm volatile("s_waitcnt vmcnt(0)" ::: "memory");   // K-lds + V-reg loads done
    writeV(cur ^ 1);                                   // safe: readers gone since last barrier
    __syncthreads();
  }

  // normalize + store
#pragma unroll
  for (int mi = 0; mi < 2; ++mi)
#pragma unroll
    for (int r = 0; r < 4; ++r) {
      const float lr_r = __shfl(lrun[mi], (l & 48) | (((l >> 4) & 3) << 2) | r);
      const float inv = 1.0f / lr_r;
      const int row = q0 + mi * 16 + (l >> 4) * 4 + r;
#pragma unroll
      for (int f = 0; f < 4; ++f)
        Ao[(size_t)(b * SEQ + row) * D_MODEL + hoff + f * 16 + lr] = f2bf(acc[mi][f][r] * inv);
    }
}

// ---------------- launch ----------------
// ws layout (shorts): xb[nMD] qp[nMD] kp[nMD] vp[nMD] wb[nDD] wob[nDD]  (~71 MB)
extern "C" void kernel_launch(void* const* d_in, const int* in_sizes, int n_in,
                              void* d_out, int out_size, void* d_ws, size_t ws_size,
                              hipStream_t stream) {
  const float* q  = (const float*)d_in[0];
  const float* k  = (const float*)d_in[1];
  const float* v  = (const float*)d_in[2];
  const float* wq = (const float*)d_in[3];
  const float* bq = (const float*)d_in[4];
  const float* wk = (const float*)d_in[5];
  const float* bk = (const float*)d_in[6];
  const float* wv = (const float*)d_in[7];
  const float* bv = (const float*)d_in[8];
  const float* wo = (const float*)d_in[9];
  const float* bo = (const float*)d_in[10];
  float* out = (float*)d_out;

  const int M = BATCH * SEQ;            // 8192
  const int D = D_MODEL;                // 1024
  const size_t nMD = (size_t)M * D;
  const size_t nDD = (size_t)D * D;
  const int nbW = (int)(nDD / 2048);    // 512
  const int nbX = (int)(nMD / 2048);    // 4096

  unsigned short* ws  = (unsigned short*)d_ws;
  unsigned short* xb  = ws;             // bf16 input (reused), then attn out
  unsigned short* qp  = xb + nMD;
  unsigned short* kp  = qp + nMD;
  unsigned short* vp  = kp + nMD;
  unsigned short* wb  = vp + nMD;       // bf16 weight (reused q->k->v)
  unsigned short* wob = wb + nDD;       // bf16 W_o
  unsigned short* ao  = xb;

  dim3 gg(512);

  cvtseg<<<nbW + nbX, 256, 0, stream>>>(wq, wb, nbW, q, xb, nbX, wq, wb);
  gemm_bt<0><<<gg, 256, 0, stream>>>(xb, wb, bq, qp, nullptr, M, D, D);

  cvtseg<<<nbW + nbX, 256, 0, stream>>>(wk, wb, nbW, k, xb, nbX, wk, wb);
  gemm_bt<0><<<gg, 256, 0, stream>>>(xb, wb, bk, kp, nullptr, M, D, D);

  cvtseg<<<nbW + nbX + nbW, 256, 0, stream>>>(wv, wb, nbW, v, xb, nbX, wo, wob);
  gemm_bt<0><<<gg, 256, 0, stream>>>(xb, wb, bv, vp, nullptr, M, D, D);

  attn_fwd<<<dim3(1024), 256, 0, stream>>>(qp, kp, vp, ao);

  gemm_bt<1><<<gg, 256, 0, stream>>>(ao, wob, bo, nullptr, out, M, D, D);
}